// Round 1
// baseline (2789.096 us; speedup 1.0000x reference)
//
#include <hip/hip_runtime.h>
#include <cstdint>
#include <cstddef>

#define DI __device__ __forceinline__

typedef __bf16 bf16x8 __attribute__((ext_vector_type(8)));
typedef float  f32x4  __attribute__((ext_vector_type(4)));
typedef unsigned short ushort_t;

constexpr int BATCH = 1024;
constexpr int HID   = 2048;
constexpr int IN    = 76;
constexpr int SENC  = 49;
constexpr int TDEC  = 25;
constexpr int KX    = 128;          // x padded to 128 cols
constexpr int KP    = KX + HID;     // 2176 packed K
constexpr int BK    = 64;
constexpr int KTT   = KP / BK;      // 34 K-steps
constexpr int OSTR  = TDEC * IN;    // 1900 (row stride of decoder_inputs and d_out)

DI unsigned short f2bf(float f) {
  union { float f; unsigned u; } v; v.f = f;
  unsigned u = v.u;
  return (unsigned short)((u + 0x7fffu + ((u >> 16) & 1u)) >> 16);  // RTNE
}

DI f32x4 mfma16(bf16x8 a, bf16x8 b, f32x4 c) {
  return __builtin_amdgcn_mfma_f32_16x16x32_bf16(a, b, c, 0, 0, 0);
}

DI void gload_lds16(const void* g, void* l) {
  __builtin_amdgcn_global_load_lds((const __attribute__((address_space(1))) void*)g,
                                   (__attribute__((address_space(3))) void*)l,
                                   16, 0, 0);
}

DI float sigmoidf_(float x) { return 1.0f / (1.0f + __expf(-x)); }
DI float tanhf_(float x)    { return 1.0f - 2.0f / (1.0f + __expf(2.0f * x)); }

// ---------------- packing kernels (run once per launch) ----------------

// Wp[n][k] (6144 x 2176) bf16 = [W_ih | zeros(52) | W_hh]
__global__ void pack_W(const float* __restrict__ Wih, const float* __restrict__ Whh,
                       ushort_t* __restrict__ Wp) {
  int idx = blockIdx.x * 256 + threadIdx.x;
  if (idx >= 6144 * KP) return;
  int n = idx / KP;
  int k = idx - n * KP;
  float v = 0.f;
  if (k < IN)        v = Wih[(size_t)n * IN + k];
  else if (k >= KX)  v = Whh[(size_t)n * HID + (k - KX)];
  Wp[idx] = f2bf(v);
}

// xe[t][b][128] bf16, zero-padded
__global__ void pack_xe(const float* __restrict__ enc, ushort_t* __restrict__ xe) {
  int idx = blockIdx.x * 256 + threadIdx.x;
  if (idx >= SENC * BATCH * KX) return;
  int t = idx >> 17;            // 1024*128 = 131072 = 2^17
  int rem = idx & 131071;
  int b = rem >> 7, k = rem & 127;
  float v = (k < IN) ? enc[(size_t)b * (SENC * IN) + t * IN + k] : 0.f;
  xe[idx] = f2bf(v);
}

// xd[b][128] bf16 from decoder_inputs[:,0,:]
__global__ void pack_xd0(const float* __restrict__ dec, ushort_t* __restrict__ xd) {
  int idx = blockIdx.x * 256 + threadIdx.x;
  if (idx >= BATCH * KX) return;
  int b = idx >> 7, k = idx & 127;
  float v = (k < IN) ? dec[(size_t)b * OSTR + k] : 0.f;
  xd[idx] = f2bf(v);
}

// Wfc[80][2048] bf16, rows 76..79 zero
__global__ void pack_fc(const float* __restrict__ fcw, ushort_t* __restrict__ Wfc) {
  int idx = blockIdx.x * 256 + threadIdx.x;
  if (idx >= 80 * HID) return;
  int n = idx >> 11, k = idx & 2047;
  float v = (n < IN) ? fcw[(size_t)n * HID + k] : 0.f;
  Wfc[idx] = f2bf(v);
}

// ---------------- fused GRU step: g = [x|h] @ Wp^T, gates, h_new ----------------
// grid 256 (8 m-groups x 32 n-groups), block 512 (8 waves, 4x2 over 128x64 tile)
__global__ __launch_bounds__(512, 2) void gru_step_kernel(
    const ushort_t* __restrict__ x,    // [1024][128] bf16
    const ushort_t* __restrict__ hbp,  // [1024][2048] bf16 h_prev
    const float*    __restrict__ hfp,  // [1024][2048] f32  h_prev
    const ushort_t* __restrict__ Wp,   // [6144][2176] bf16
    const float*    __restrict__ b_ih,
    const float*    __restrict__ b_hh,
    float*          __restrict__ hfn,  // [1024][2048] f32  h_new
    ushort_t*       __restrict__ hbn)  // [1024][2048] bf16 h_new
{
  __shared__ ushort_t lds[2][(128 + 192) * BK];   // A 128x64 + B 192x64, double buffered = 80 KB

  const int tid  = threadIdx.x;
  const int lane = tid & 63;
  const int wid  = tid >> 6;
  const int bid  = blockIdx.x;
  // XCD swizzle: n-group constant per XCD (bid%8) -> W panel reused from one L2
  const int n_grp = (bid & 7) + 8 * (bid >> 6);   // 0..31
  const int m_grp = (bid >> 3) & 7;               // 0..7
  const int row0  = m_grp * 128;
  const int col0  = n_grp * 64;
  const int wm = wid >> 1, wn = wid & 1;

  // staging constants: chunk row = lane>>3, source col XOR-preswizzled so that the
  // linear global_load_lds destination holds the (row&7)-XOR-swizzled layout
  const int srow  = lane >> 3;
  const int swcol = (((lane & 7) ^ (srow & 7)) << 3);   // elements

  const f32x4 Z4 = {0.f, 0.f, 0.f, 0.f};
  f32x4 accr[2][2], accz[2][2], accin[2][2], accN[2][2];
  #pragma unroll
  for (int a = 0; a < 2; ++a)
    #pragma unroll
    for (int b = 0; b < 2; ++b) { accr[a][b] = Z4; accz[a][b] = Z4; accin[a][b] = Z4; accN[a][b] = Z4; }

  // fragment-read constants (consumer-side XOR swizzle)
  const int lr  = lane & 15;
  const int bc  = (lane >> 4) * 16;                       // byte col, pre-swizzle
  const int ksw0 = ((bc)      ^ ((lane & 7) << 4)) >> 1;  // element offsets
  const int ksw1 = ((64 + bc) ^ ((lane & 7) << 4)) >> 1;

  auto stage = [&](int buf, int kt) {
    const ushort_t* asrc; int astr, ak0;
    if (kt < 2) { asrc = x;   astr = KX;  ak0 = kt * BK; }
    else        { asrc = hbp; astr = HID; ak0 = (kt - 2) * BK; }
    ushort_t* Lb = &lds[buf][0];
    #pragma unroll
    for (int c = 0; c < 2; ++c) {                 // A: 2 chunks/wave (1 KB each)
      const int chunk = wid * 2 + c;
      const ushort_t* g = asrc + (size_t)(row0 + chunk * 8 + srow) * astr + ak0 + swcol;
      gload_lds16(g, Lb + chunk * 512);
    }
    const int wk0 = kt * BK;
    #pragma unroll
    for (int c = 0; c < 3; ++c) {                 // B: 3 chunks/wave
      const int chunk = wid * 3 + c;
      const int brow = chunk * 8 + srow;          // 0..191 (gate*64 + col)
      const int gg = brow >> 6, wi = brow & 63;
      const ushort_t* g = Wp + (size_t)(gg * HID + col0 + wi) * KP + wk0 + swcol;
      gload_lds16(g, Lb + 128 * BK + chunk * 512);
    }
  };

  stage(0, 0);

  for (int kt = 0; kt < KTT; ++kt) {
    if (kt + 1 < KTT) {
      stage((kt + 1) & 1, kt + 1);
      asm volatile("s_waitcnt vmcnt(5)" ::: "memory");  // drain current tile's 5 loads only
    } else {
      asm volatile("s_waitcnt vmcnt(0)" ::: "memory");
    }
    __builtin_amdgcn_s_barrier();

    {
      const ushort_t* Ab = &lds[kt & 1][0];
      const ushort_t* Bb = &lds[kt & 1][128 * BK];
      #pragma unroll
      for (int ks = 0; ks < 2; ++ks) {
        const int ko = ks ? ksw1 : ksw0;
        bf16x8 af[2], bg[3][2];
        #pragma unroll
        for (int fm = 0; fm < 2; ++fm)
          af[fm] = *reinterpret_cast<const bf16x8*>(&Ab[(wm * 32 + fm * 16 + lr) * BK + ko]);
        #pragma unroll
        for (int g = 0; g < 3; ++g)
          #pragma unroll
          for (int fn = 0; fn < 2; ++fn)
            bg[g][fn] = *reinterpret_cast<const bf16x8*>(&Bb[(g * 64 + wn * 32 + fn * 16 + lr) * BK + ko]);
        #pragma unroll
        for (int fm = 0; fm < 2; ++fm)
          #pragma unroll
          for (int fn = 0; fn < 2; ++fn) {
            accr[fm][fn] = mfma16(af[fm], bg[0][fn], accr[fm][fn]);
            accz[fm][fn] = mfma16(af[fm], bg[1][fn], accz[fm][fn]);
            accN[fm][fn] = mfma16(af[fm], bg[2][fn], accN[fm][fn]);
          }
      }
    }
    if (kt == 1) {   // n-gate: save x-part (i_n), restart accumulator for h-part (h_n)
      #pragma unroll
      for (int a = 0; a < 2; ++a)
        #pragma unroll
        for (int b = 0; b < 2; ++b) { accin[a][b] = accN[a][b]; accN[a][b] = Z4; }
    }
    __builtin_amdgcn_s_barrier();
  }

  // epilogue: gates + recurrence (C/D layout: col = lane&15, row = (lane>>4)*4 + q)
  const int lqb = (lane >> 4) * 4;
  #pragma unroll
  for (int fn = 0; fn < 2; ++fn) {
    const int j = col0 + wn * 32 + fn * 16 + lr;
    const float br  = b_ih[j] + b_hh[j];
    const float bz  = b_ih[HID + j] + b_hh[HID + j];
    const float bin = b_ih[2 * HID + j];
    const float bhn = b_hh[2 * HID + j];
    #pragma unroll
    for (int fm = 0; fm < 2; ++fm) {
      #pragma unroll
      for (int q = 0; q < 4; ++q) {
        const int row = row0 + wm * 32 + fm * 16 + lqb + q;
        const size_t off = (size_t)row * HID + j;
        const float hp = hfp[off];
        const float rr = sigmoidf_(accr[fm][fn][q] + br);
        const float zz = sigmoidf_(accz[fm][fn][q] + bz);
        const float nn = tanhf_(accin[fm][fn][q] + bin + rr * (accN[fm][fn][q] + bhn));
        const float hv = (1.0f - zz) * nn + zz * hp;
        hfn[off] = hv;
        hbn[off] = f2bf(hv);
      }
    }
  }
}

// ---------------- decoder fc: out = prev + h_new @ fc_w^T + fc_b; also emit next x (bf16) ----
// grid 64 (16 batch rows each), block 256 (4 waves split K=2048 into 512-chunks)
__global__ __launch_bounds__(256) void fc_kernel(
    const ushort_t* __restrict__ hb,    // [1024][2048] bf16 h_new
    const ushort_t* __restrict__ Wfc,   // [80][2048] bf16
    const float*    __restrict__ fc_b,
    const float*    __restrict__ prev,  // row stride OSTR
    float*          __restrict__ outp,  // d_out + t*IN, row stride OSTR
    ushort_t*       __restrict__ xd)    // [1024][128] bf16 next input
{
  __shared__ float red[4][16][80];
  const int tid = threadIdx.x, lane = tid & 63, wid = tid >> 6;
  const int r0 = blockIdx.x * 16;
  const int lr = lane & 15, lk = (lane >> 4) * 8;
  const f32x4 Z4 = {0.f, 0.f, 0.f, 0.f};
  f32x4 acc[5];
  #pragma unroll
  for (int f = 0; f < 5; ++f) acc[f] = Z4;
  const int kbase = wid * 512;
  #pragma unroll
  for (int ks = 0; ks < 16; ++ks) {
    const int k = kbase + ks * 32 + lk;
    bf16x8 a = *reinterpret_cast<const bf16x8*>(&hb[(size_t)(r0 + lr) * HID + k]);
    #pragma unroll
    for (int f = 0; f < 5; ++f) {
      bf16x8 b = *reinterpret_cast<const bf16x8*>(&Wfc[(size_t)(f * 16 + lr) * HID + k]);
      acc[f] = mfma16(a, b, acc[f]);
    }
  }
  #pragma unroll
  for (int f = 0; f < 5; ++f)
    #pragma unroll
    for (int q = 0; q < 4; ++q)
      red[wid][(lane >> 4) * 4 + q][f * 16 + lr] = acc[f][q];
  __syncthreads();

  const int rowi = tid >> 4;          // 0..15
  const int j0   = (tid & 15) * 8;    // 0..120
  const int b_   = r0 + rowi;
  #pragma unroll
  for (int jj = 0; jj < 8; ++jj) {
    const int j = j0 + jj;
    float ov = 0.f;
    if (j < IN) {
      float s = red[0][rowi][j] + red[1][rowi][j] + red[2][rowi][j] + red[3][rowi][j];
      ov = prev[(size_t)b_ * OSTR + j] + fc_b[j] + s;
      outp[(size_t)b_ * OSTR + j] = ov;
    }
    xd[b_ * KX + j] = f2bf(j < IN ? ov : 0.f);
  }
}

// ---------------- host launch ----------------
extern "C" void kernel_launch(void* const* d_in, const int* in_sizes, int n_in,
                              void* d_out, int out_size, void* d_ws, size_t ws_size,
                              hipStream_t stream) {
  const float* enc = (const float*)d_in[0];
  const float* dec = (const float*)d_in[1];
  const float* Wih = (const float*)d_in[2];
  const float* Whh = (const float*)d_in[3];
  const float* bih = (const float*)d_in[4];
  const float* bhh = (const float*)d_in[5];
  const float* fcw = (const float*)d_in[6];
  const float* fcb = (const float*)d_in[7];
  float* out = (float*)d_out;

  char* ws = (char*)d_ws;
  ushort_t* Wp  = (ushort_t*)ws;  ws += (size_t)6144 * KP * 2;          // 26.7 MB
  ushort_t* xe  = (ushort_t*)ws;  ws += (size_t)SENC * BATCH * KX * 2;  // 12.8 MB
  ushort_t* xd  = (ushort_t*)ws;  ws += (size_t)BATCH * KX * 2;         // 256 KB
  ushort_t* Wfc = (ushort_t*)ws;  ws += (size_t)80 * HID * 2;           // 320 KB
  float* hf0 = (float*)ws;        ws += (size_t)BATCH * HID * 4;
  float* hf1 = (float*)ws;        ws += (size_t)BATCH * HID * 4;
  ushort_t* hb0 = (ushort_t*)ws;  ws += (size_t)BATCH * HID * 2;
  ushort_t* hb1 = (ushort_t*)ws;  ws += (size_t)BATCH * HID * 2;
  float* hf[2] = {hf0, hf1};
  ushort_t* hbp[2] = {hb0, hb1};

  pack_W  <<<(6144 * KP + 255) / 256, 256, 0, stream>>>(Wih, Whh, Wp);
  pack_xe <<<(SENC * BATCH * KX + 255) / 256, 256, 0, stream>>>(enc, xe);
  pack_xd0<<<(BATCH * KX + 255) / 256, 256, 0, stream>>>(dec, xd);
  pack_fc <<<(80 * HID + 255) / 256, 256, 0, stream>>>(fcw, Wfc);
  hipMemsetAsync(hf0, 0, (size_t)BATCH * HID * 4, stream);
  hipMemsetAsync(hb0, 0, (size_t)BATCH * HID * 2, stream);

  for (int s = 0; s < SENC + TDEC; ++s) {
    const ushort_t* xsrc = (s < SENC) ? (xe + (size_t)s * BATCH * KX) : xd;
    gru_step_kernel<<<256, 512, 0, stream>>>(xsrc, hbp[s & 1], hf[s & 1], Wp, bih, bhh,
                                             hf[(s + 1) & 1], hbp[(s + 1) & 1]);
    if (s >= SENC) {
      const int t = s - SENC;
      const float* prev = (t == 0) ? dec : (out + (size_t)(t - 1) * IN);
      fc_kernel<<<64, 256, 0, stream>>>(hbp[(s + 1) & 1], Wfc, fcb, prev,
                                        out + (size_t)t * IN, xd);
    }
  }
}